// Round 6
// baseline (147.209 us; speedup 1.0000x reference)
//
#include <hip/hip_runtime.h>
#include <stdint.h>

// Round 16: 2D lane map (unconfounded retest) + nontemporal full-line stores.
// Base compute = r15 (quad-gather, zero-seg, segsafe de-clamp, pipelined
// loads) — three-path body byte-identical, now at 1 segment of 4 px per
// thread.
//
// vs r15:
//  (1) lane map 1D -> 2D: tx=lane&7 (4-px seg; 8 lanes x 16B = one FULL
//      128B line per store instr), ty=lane>>3 (8 rows per wave). Block =
//      32 rows x 32 px, grid = 8*32*64 = 16384. Wave quad-load footprint
//      drops from ~64 lines/instr (iy spread 16|t3| quad rows across the
//      wave) to ~(4|t0|+1)x(2|t3|+|t4|+1) cells total -> L1 line-
//      serialization ~3-6x lower. r13's null for this map was confounded
//      by the (then-broken) stores.
//  (2) nontemporal restored: stores are full 128B lines now (nothing to
//      RMW), and NT keeps the 134MB output stream out of L2 so the 4.3MB
//      Q image stays L2-resident for the gather side.
// fp32 in / fp32 out. gt_up[y,x] == gt[y>>3, x>>3] (never materialized).

typedef float vfloat4 __attribute__((ext_vector_type(4)));

constexpr int BATCH = 8;
constexpr int HI = 128, WI = 256;
constexpr int HO = 1024, WO = 2048;
constexpr size_t NPIX = (size_t)BATCH * HO * WO;   // 16777216 per output

// Quad image: Q[y+1][x+1] = (P[y][x], P[y][x+1], P[y+1][x], P[y+1][x+1]),
// P = zero-padded gt. Row index cy0+1 in [0,129], col cx0+1 in [0,257].
constexpr int QH = HI + 2;
constexpr int QW = WI + 2;
constexpr size_t QIMG = (size_t)QH * QW;           // quads per image

__global__ __launch_bounds__(256) void pad4_kernel(
    const float* __restrict__ gt, vfloat4* __restrict__ Q)
{
    const int i = blockIdx.x * 256 + threadIdx.x;  // over BATCH*QIMG
    if (i >= (int)(BATCH * QIMG)) return;
    const int b = i / (int)QIMG;
    const int r = i - b * (int)QIMG;
    const int y = r / QW - 1;                      // [-1, HI]
    const int x = r - (r / QW) * QW - 1;           // [-1, WI]
    const float* __restrict__ g = gt + (size_t)b * (HI * WI);
    auto val = [&](int yy, int xx) -> float {
        return (yy >= 0 && yy < HI && xx >= 0 && xx < WI)
                   ? g[yy * WI + xx] : 0.0f;
    };
    vfloat4 q = { val(y, x), val(y, x + 1), val(y + 1, x), val(y + 1, x + 1) };
    Q[i] = q;
}

__global__ __launch_bounds__(256) void stn_kernel(
    const float* __restrict__ gt,     // [B, HI, WI] (boxy path)
    const float* __restrict__ theta,  // [B, 6]
    const vfloat4* __restrict__ Q,    // quad images in d_ws
    float* __restrict__ out)          // [2, B, HO, WO] f32
{
    // Block tile: 32 rows x 32 px. Grid = 8 b * 32 ytiles * 64 xtiles.
    const int bid = blockIdx.x;
    const int xt = bid & 63;               // x-tile (32 px)
    const int yt = (bid >> 6) & 31;        // y-tile (32 rows)
    const int b  = bid >> 11;
    const int tx = threadIdx.x & 7;        // 4-px segment within 32-px tile
    const int ty = threadIdx.x >> 3;       // row within tile (0..31)
    const int h  = yt * 32 + ty;
    const int w0 = xt * 32 + tx * 4;
    const int row = (b << 10) + h;         // b*HO + h

    const float* tb = theta + b * 6;
    const float t0 = tb[0], t1 = tb[1], t2 = tb[2];
    const float t3 = tb[3], t4 = tb[4], t5 = tb[5];
    const float* __restrict__ gtb = gt + b * (HI * WI);
    // Pre-offset so index is cy0*QW + cx0 (pad ring at cy0=-1 / cx0=-1 ok).
    const vfloat4* __restrict__ Qb = Q + (size_t)b * QIMG + QW + 1;

    const float ys = (h + 0.5f) * (2.0f / (float)HO) - 1.0f;
    const float dix = t0;
    const float diy = 0.5f * t3;

    // ---------------- boxy: one scalar per 4-px group ----------------
    {
        const float gy2 = t4 * ys + t5;
        const float iyy = ((gy2 + 1.0f) * (float)HO - 1.0f) * 0.5f;
        const float fyy = floorf(iyy);
        const float wyy = iyy - fyy;
        const float vy0 = (fyy >= 0.0f && fyy <= (float)(HO - 1)) ? 1.0f : 0.0f;
        const float vy1 = (fyy >= -1.0f && fyy <= (float)(HO - 2)) ? 1.0f : 0.0f;
        const int y0 = ((int)fminf(fmaxf(fyy,        0.0f), (float)(HO - 1))) >> 3;
        const int y1 = ((int)fminf(fmaxf(fyy + 1.0f, 0.0f), (float)(HO - 1))) >> 3;
        const int cell = w0 >> 3;          // 4-px group never straddles a cell
        const float s0 = gtb[y0 * WI + cell];
        const float s1 = gtb[y1 * WI + cell];
        const float byv = s0 * ((1.0f - wyy) * vy0) + s1 * (wyy * vy1);
        const vfloat4 vb = {byv, byv, byv, byv};
        vfloat4* dst = reinterpret_cast<vfloat4*>(out + NPIX + (size_t)row * WO + w0);
        __builtin_nontemporal_store(vb, dst);   // full 128B line per 8-lane group
    }

    // ---------------- box: 4 px bilinear via one quad load each ----------------
    const float xn0 = (w0 + 0.5f) * (2.0f / (float)WO) - 1.0f;
    const float gx0 = t0 * xn0 + (t1 * ys + t2);
    const float gy0 = t3 * xn0 + (t4 * ys + t5);
    const float ix0 = ((gx0 + 1.0f) * (float)WO - 1.0f) * 0.5f;  // step t0 per px
    const float iy0 = ((gy0 + 1.0f) * (float)HO - 1.0f) * 0.5f;  // step t3/2 per px

    const float ixe = ix0 + 3.0f * dix;
    const float iye = iy0 + 3.0f * diy;
    const float ixmin = fminf(ix0, ixe), ixmax = fmaxf(ix0, ixe);
    const float iymin = fminf(iy0, iye), iymax = fmaxf(iy0, iye);
    const bool segzero = (ixmax < -1.0f) || (ixmin >= (float)WO) ||
                         (iymax < -1.0f) || (iymin >= (float)HO);
    const bool segsafe = (ixmin >= -1.0f) && (ixmax < (float)WO) &&
                         (iymin >= -1.0f) && (iymax < (float)HO);

    float px[4];
    if (segzero) {
#pragma unroll
        for (int p = 0; p < 4; ++p) px[p] = 0.0f;
    } else if (segsafe) {
        // No clamps: xi in [-1, WO-1], shifts land in [-1,WI]/[-1,HI];
        // pad ring supplies zeros.
        vfloat4 q[4];
        float wx[4], wy[4];
        bool cxe[4], cye[4];
#pragma unroll
        for (int p = 0; p < 4; ++p) {
            const float ixp = fmaf((float)p, dix, ix0);
            const float iyp = fmaf((float)p, diy, iy0);
            const float fx = floorf(ixp), fy = floorf(iyp);
            wx[p] = ixp - fx;  wy[p] = iyp - fy;
            const int xi = (int)fx, yi = (int)fy;
            const int cx0 = xi >> 3;
            const int cx1 = (xi + 1) >> 3;
            const int cy0 = yi >> 3;
            const int cy1 = (yi + 1) >> 3;
            cxe[p] = (cx1 == cx0);
            cye[p] = (cy1 == cy0);
            q[p] = Qb[cy0 * QW + cx0];
        }
#pragma unroll
        for (int p = 0; p < 4; ++p) {
            const float a  = q[p].x;
            const float bb = cxe[p] ? q[p].x : q[p].y;   // P[cy0][cx1]
            const float c  = cye[p] ? q[p].x : q[p].z;   // P[cy1][cx0]
            const float dl = cxe[p] ? q[p].z : q[p].w;
            const float d  = cye[p] ? bb     : dl;       // P[cy1][cx1]
            const float h0 = fmaf(wx[p], bb - a, a);
            const float h1 = fmaf(wx[p], d - c,  c);
            px[p] = fmaf(wy[p], h1 - h0, h0);
        }
    } else {
        // General clamped path (segment straddles a boundary) — r12 logic.
        float ix = ix0, iy = iy0;
#pragma unroll
        for (int p = 0; p < 4; ++p) {
            const float fx = floorf(ix), fy = floorf(iy);
            const float wx = ix - fx,    wy = iy - fy;
            const int xi = (int)fx, yi = (int)fy;    // cvt saturates at extremes
            const int cx0 = min(max(xi >> 3,       -1), WI);
            const int cx1 = min(max((xi + 1) >> 3, -1), WI);
            const int cy0 = min(max(yi >> 3,       -1), HI);
            const int cy1 = min(max((yi + 1) >> 3, -1), HI);
            const vfloat4 q = Qb[cy0 * QW + cx0];
            const bool cxe = (cx1 == cx0);
            const bool cye = (cy1 == cy0);
            const float a  = q.x;
            const float bb = cxe ? q.x : q.y;        // P[cy0][cx1]
            const float c  = cye ? q.x : q.z;        // P[cy1][cx0]
            const float dl = cxe ? q.z : q.w;
            const float d  = cye ? bb  : dl;         // P[cy1][cx1]
            const float h0 = fmaf(wx, bb - a, a);
            const float h1 = fmaf(wx, d - c,  c);
            px[p] = fmaf(wy, h1 - h0, h0);
            ix += dix; iy += diy;
        }
    }
    const vfloat4 v = {px[0], px[1], px[2], px[3]};
    vfloat4* dst = reinterpret_cast<vfloat4*>(out + (size_t)row * WO + w0);
    __builtin_nontemporal_store(v, dst);       // full 128B line per 8-lane group
}

extern "C" void kernel_launch(void* const* d_in, const int* in_sizes, int n_in,
                              void* d_out, int out_size, void* d_ws, size_t ws_size,
                              hipStream_t stream) {
    const float* gt    = (const float*)d_in[0];
    const float* theta = (const float*)d_in[1];
    float* out = (float*)d_out;
    vfloat4* Q = (vfloat4*)d_ws;   // 8*130*258*16 B ~= 4.3 MB << ws_size

    const int qN = (int)(BATCH * QIMG);
    pad4_kernel<<<(qN + 255) / 256, 256, 0, stream>>>(gt, Q);
    stn_kernel<<<BATCH * 32 * 64, 256, 0, stream>>>(gt, theta, Q, out);
}